// Round 1
// 3484.108 us; speedup vs baseline: 1.7393x; 1.7393x over previous
//
#include <hip/hip_runtime.h>

#define T_SEQ   1024
#define T_STEPS 1023
#define BATCH   128
#define DIM     256
#define HID     1024
#define VOUT    128
#define NKK     40       // K fragments of 32: 8 (x) + 32 (h)
#define WGS     256
#define HSLOT   131072   // ushorts per t-slot: 8 slices x 16384
#define SLICE_E 16384    // h elems per slice per t (16 rows x 1024), blocked [kk][lq][row][j]
#define XSLICE  4096     // x elems per slice per t (16 rows x 256),  blocked [kk][lq][row][j]

typedef __attribute__((ext_vector_type(8))) short short8;
typedef __attribute__((ext_vector_type(4))) float floatx4;

// async global->LDS, 16B per lane; LDS dest is wave-uniform base + lane*16 which
// coincides with passing &lds[tid*8] (linear copy).
#define GLDS(gp, lp) __builtin_amdgcn_global_load_lds( \
    (const __attribute__((address_space(1))) unsigned int*)(gp), \
    (__attribute__((address_space(3))) unsigned int*)(lp), 16, 0, 0)

__device__ __forceinline__ unsigned short f2bf(float x) {
    union { float f; unsigned u; } v; v.f = x;
    unsigned r = v.u + 0x7FFFu + ((v.u >> 16) & 1u);   // RNE
    return (unsigned short)(r >> 16);
}
__device__ __forceinline__ float sigm(float x) { return 1.0f / (1.0f + __expf(-x)); }

// ---------------- prep kernels ----------------

// Weights bf16 in wave-fragment order for the slice design.
// Layout: [cg 0..31][w 0..7][i 0..39][lane 0..63][j 0..7], w = cw*4+kw, i = ct*10+kki.
// B-frag elem: col gc = cw*64 + ct*16 + (lane&15) (local gate col of the WG),
//              k = (kw*10 + kki)*32 + (lane>>4)*8 + j.
// W row R = gate*H + cg*32 + hcol_local, gate = gc>>5, hcol_local = gc&31.
__global__ void pack_w(const float* __restrict__ Wih, const float* __restrict__ Whh,
                       unsigned short* __restrict__ Wp) {
    const size_t idx = (size_t)blockIdx.x * 256 + threadIdx.x;
    if (idx >= (size_t)32 * 8 * NKK * 64 * 8) return;   // 5,242,880
    const int j   = (int)(idx & 7);
    const int l   = (int)((idx >> 3) & 63);
    const int rest = (int)(idx >> 9);
    const int i   = rest % NKK;
    const int wcg = rest / NKK;
    const int w   = wcg & 7;
    const int cg  = wcg >> 3;
    const int cw = w >> 2, kw = w & 3;
    const int ct = i / 10, kki = i % 10;
    const int gc = cw * 64 + ct * 16 + (l & 15);
    const int R  = (gc >> 5) * HID + cg * 32 + (gc & 31);
    const int k  = (kw * 10 + kki) * 32 + (l >> 4) * 8 + j;
    const float v = (k < DIM) ? Wih[(size_t)R * DIM + k] : Whh[(size_t)R * HID + (k - DIM)];
    Wp[idx] = f2bf(v);
}

// bias in natural (gate*H + hcol) order
__global__ void pack_bias(const float* __restrict__ bih, const float* __restrict__ bhh,
                          float* __restrict__ bc) {
    const int idx = blockIdx.x * 256 + threadIdx.x;
    if (idx < 4096) bc[idx] = bih[idx] + bhh[idx];
}

__global__ void pack_wout(const float* __restrict__ Wo, unsigned short* __restrict__ WoBf) {
    const int idx = blockIdx.x * 256 + threadIdx.x;
    if (idx < VOUT * HID) WoBf[idx] = f2bf(Wo[idx]);
}

// sequence [B, T, D] fp32 -> Xb [t][s8][kk 8][lq 4][row 16][j 8] bf16 (slice-blocked)
__global__ void pack_x(const float* __restrict__ seq, unsigned short* __restrict__ Xb) {
    const size_t idx = (size_t)blockIdx.x * 256 + threadIdx.x;
    if (idx >= (size_t)T_STEPS * BATCH * DIM) return;
    const int j   = (int)(idx & 7);
    const int row = (int)((idx >> 3) & 15);
    const int lq  = (int)((idx >> 7) & 3);
    const int kk  = (int)((idx >> 9) & 7);
    const int s8  = (int)((idx >> 12) & 7);
    const int t   = (int)(idx >> 15);
    const int b = s8 * 16 + row;
    const int k = kk * 32 + lq * 8 + j;
    Xb[idx] = f2bf(seq[((size_t)b * T_SEQ + t) * DIM + k]);
}

__global__ void init_state(unsigned short* __restrict__ Hb, int* __restrict__ bar) {
    const int idx = blockIdx.x * 256 + threadIdx.x;
    if (idx < HSLOT) Hb[idx] = 0;          // t=0 slot zeros
    if (idx < 4096) bar[idx] = 0;          // per-slice barrier counters
}

// ---------------- persistent recurrent kernel ----------------
// 256 WGs x 512 threads, 1 WG/CU. Batch sliced 8x16: slice s8 = wg&7 owned by 32
// WGs (cg = wg>>3 -> h-cols [cg*32,cg*32+32)). ALL weights in VGPRs (160/wave).
// Wave (cw,kw): 64 gate cols x K-slice 320. h/x staged to LDS via global_load_lds,
// consumed as linear ds_read_b128 frags. Per-slice 32-WG IC barrier per step.
__global__ __launch_bounds__(512, 1) void lstm_persist(
    const unsigned short* __restrict__ Xb,
    unsigned short* __restrict__ Hblk,
    const unsigned short* __restrict__ Wp,
    const float* __restrict__ bc,
    int* __restrict__ bar)
{
    __shared__ short8 hl[2048];      // 32 KB  h(t) slice, blocked
    __shared__ short8 xl[512];       // 8 KB   x(t) slice, blocked
    __shared__ float  gl[4][16][132];// 33 KB  per-kw gate partials (padded)
    __shared__ int abortf;

    const int wg  = blockIdx.x;
    const int s8  = wg & 7;          // slice (== XCD under round-robin heuristic)
    const int cg  = wg >> 3;         // h-col group of 32 within slice
    const int tid = threadIdx.x;
    const int w   = tid >> 6;
    const int l   = tid & 63;
    const int lr  = l & 15;
    const int lq  = l >> 4;
    const int cw  = w >> 2;          // col half: 64 gate cols
    const int kw  = w & 3;           // K quarter: frags [kw*10, kw*10+10)
    const int cbase = cw * 64;
    const int lq4 = lq * 4;

    // ---- B fragments to registers: 40 x short8 = 160 VGPRs ----
    const short8* wpw = (const short8*)Wp + (size_t)(cg * 8 + w) * NKK * 64 + l;
    short8 breg[NKK];
    #pragma unroll
    for (int i = 0; i < NKK; ++i) breg[i] = wpw[i * 64];

    // epilogue ids: tid = elq*128 + er*8 + ej  -> cell (row er, h-col hc=elq*8+ej)
    const int er  = (tid >> 3) & 15;
    const int ej  = tid & 7;
    const int elq = tid >> 7;
    const int hc  = elq * 8 + ej;
    const float bi  = bc[0 * HID + cg * 32 + hc];
    const float bf_ = bc[1 * HID + cg * 32 + hc];
    const float bg  = bc[2 * HID + cg * 32 + hc];
    const float bo_ = bc[3 * HID + cg * 32 + hc];
    float creg = 0.f;

    if (tid == 0) abortf = 0;
    // prefetch x(0)
    GLDS(Xb + (size_t)s8 * XSLICE + tid * 8, (unsigned short*)xl + tid * 8);

    long budget = 1L << 22;
    int* cnt = &bar[s8 * 64];
    const short8* xv = xl + l;
    const short8* hv = hl + l;

    for (int t = 0; t < T_STEPS; ++t) {
        // ---- stage h(t) slice: 4 x 16B per thread, linear copy ----
        {
            const unsigned short* hs = Hblk + (size_t)t * HSLOT + (size_t)s8 * SLICE_E;
            #pragma unroll
            for (int i = 0; i < 4; ++i)
                GLDS(hs + i * 4096 + tid * 8, (unsigned short*)hl + i * 4096 + tid * 8);
        }
        __syncthreads();   // drains h(t) staging + x(t) prefetch

        // ---- MFMA: 4 col-tiles x 10 K-frags, weights from VGPR ----
        floatx4 ac0 = {0.f,0.f,0.f,0.f}, ac1 = ac0, ac2 = ac0, ac3 = ac0;
        #define STEPK(i, av) { short8 a_ = (av); \
            ac0 = __builtin_amdgcn_mfma_f32_16x16x32_bf16(a_, breg[ 0 + (i)], ac0, 0,0,0); \
            ac1 = __builtin_amdgcn_mfma_f32_16x16x32_bf16(a_, breg[10 + (i)], ac1, 0,0,0); \
            ac2 = __builtin_amdgcn_mfma_f32_16x16x32_bf16(a_, breg[20 + (i)], ac2, 0,0,0); \
            ac3 = __builtin_amdgcn_mfma_f32_16x16x32_bf16(a_, breg[30 + (i)], ac3, 0,0,0); }
        if (kw == 0) {                       // frags 0..7 = x, 8..9 = h
            #pragma unroll
            for (int i = 0; i < 8; ++i) STEPK(i, xv[i * 64]);
            #pragma unroll
            for (int i = 8; i < 10; ++i) STEPK(i, hv[(i - 8) * 64]);
        } else {                             // 10 h frags
            const short8* hb = hv + (kw * 10 - 8) * 64;
            #pragma unroll
            for (int i = 0; i < 10; ++i) STEPK(i, hb[i * 64]);
        }
        #undef STEPK

        // ---- stage gate partials (C/D: col=lane&15, row=lq*4+r) ----
        #pragma unroll
        for (int r = 0; r < 4; ++r) {
            gl[kw][lq4 + r][cbase      + lr] = ac0[r];
            gl[kw][lq4 + r][cbase + 16 + lr] = ac1[r];
            gl[kw][lq4 + r][cbase + 32 + lr] = ac2[r];
            gl[kw][lq4 + r][cbase + 48 + lr] = ac3[r];
        }
        __syncthreads();

        // ---- fused cell update: one cell per thread ----
        float gi = bi, gf = bf_, gg = bg, go = bo_;
        #pragma unroll
        for (int q = 0; q < 4; ++q) {
            gi += gl[q][er][ 0 + hc];
            gf += gl[q][er][32 + hc];
            gg += gl[q][er][64 + hc];
            go += gl[q][er][96 + hc];
        }
        const float iv = sigm(gi), fv = sigm(gf), ov = sigm(go);
        const float gv = tanhf(gg);
        creg = fv * creg + iv * gv;
        const unsigned hu = f2bf(ov * tanhf(creg));
        const unsigned up = (unsigned)__shfl_down((int)hu, 1);
        if ((tid & 1) == 0) {
            unsigned* hp = (unsigned*)(Hblk + (size_t)(t + 1) * HSLOT
                          + (size_t)s8 * SLICE_E + (size_t)cg * 512 + tid);
            __hip_atomic_store(hp, hu | (up << 16), __ATOMIC_RELAXED, __HIP_MEMORY_SCOPE_AGENT);
        }
        __syncthreads();   // drain h stores to IC before arriving

        if (t + 1 < T_STEPS) {
            // x(t+1) prefetch: latency hides under the barrier poll
            GLDS(Xb + (size_t)(t + 1) * (BATCH * DIM) + (size_t)s8 * XSLICE + tid * 8,
                 (unsigned short*)xl + tid * 8);
            if (tid == 0) {
                __hip_atomic_fetch_add(cnt, 1, __ATOMIC_RELAXED, __HIP_MEMORY_SCOPE_AGENT);
                while (__hip_atomic_load(cnt, __ATOMIC_RELAXED,
                                         __HIP_MEMORY_SCOPE_AGENT) < 32 * (t + 1)) {
                    __builtin_amdgcn_s_sleep(2);
                    if (--budget < 0) { abortf = 1; break; }
                }
            }
            __syncthreads();   // barrier done; also drains x prefetch
            if (abortf) break;
        }
    }
}

// ---------------- deferred head: logits + log-softmax ----------------
__global__ __launch_bounds__(256, 2) void head_ls(
    const unsigned short* __restrict__ Hblk,
    const unsigned short* __restrict__ Wo,
    const float* __restrict__ bo,
    float* __restrict__ out)
{
    const int bg = blockIdx.x;    // slice 0..7
    const int t  = blockIdx.y;    // 0..1022
    const int tid = threadIdx.x;
    const int w  = tid >> 6;
    const int l  = tid & 63;
    const int lr = l & 15;
    const int lq = l >> 4;
    const int b0 = bg * 16;

    // A from slice-blocked H: frag kk is 1 KB contiguous, lane l reads 16B at l*16
    const short8* ap = (const short8*)(Hblk + (size_t)(t + 1) * HSLOT
                       + (size_t)bg * SLICE_E) + l;
    const unsigned short* bp0 = Wo + (size_t)(w * 32 + lr) * HID + lq * 8;
    const unsigned short* bp1 = Wo + (size_t)(w * 32 + 16 + lr) * HID + lq * 8;

    floatx4 a0 = {0.f, 0.f, 0.f, 0.f}, a1 = {0.f, 0.f, 0.f, 0.f};
    #pragma unroll 8
    for (int kk = 0; kk < 32; ++kk) {
        short8 a   = ap[kk * 64];
        short8 b0v = *(const short8*)(bp0 + kk * 32);
        short8 b1v = *(const short8*)(bp1 + kk * 32);
        a0 = __builtin_amdgcn_mfma_f32_16x16x32_bf16(a, b0v, a0, 0, 0, 0);
        a1 = __builtin_amdgcn_mfma_f32_16x16x32_bf16(a, b1v, a1, 0, 0, 0);
    }

    __shared__ float lg[16][132];
    #pragma unroll
    for (int r = 0; r < 4; ++r) {
        lg[lq * 4 + r][w * 32 + lr]      = a0[r] + bo[w * 32 + lr];
        lg[lq * 4 + r][w * 32 + 16 + lr] = a1[r] + bo[w * 32 + 16 + lr];
    }
    __syncthreads();

    const int row = tid >> 4;
    const int c   = tid & 15;
    float vals[8];
    float m = -1e30f;
    #pragma unroll
    for (int jv = 0; jv < 8; ++jv) { vals[jv] = lg[row][c + jv * 16]; m = fmaxf(m, vals[jv]); }
    #pragma unroll
    for (int d = 8; d >= 1; d >>= 1) m = fmaxf(m, __shfl_xor(m, d, 16));
    float ssum = 0.f;
    #pragma unroll
    for (int jv = 0; jv < 8; ++jv) ssum += __expf(vals[jv] - m);
    #pragma unroll
    for (int d = 8; d >= 1; d >>= 1) ssum += __shfl_xor(ssum, d, 16);
    const float lse = m + __logf(ssum);

    float* op = out + ((size_t)(b0 + row) * T_STEPS + t) * VOUT;
    #pragma unroll
    for (int jv = 0; jv < 8; ++jv) op[c + jv * 16] = vals[jv] - lse;
}

// ---------------- launcher ----------------
extern "C" void kernel_launch(void* const* d_in, const int* in_sizes, int n_in,
                              void* d_out, int out_size, void* d_ws, size_t ws_size,
                              hipStream_t stream) {
    const float* seq  = (const float*)d_in[0];
    const float* Wih  = (const float*)d_in[1];
    const float* Whh  = (const float*)d_in[2];
    const float* bih  = (const float*)d_in[3];
    const float* bhh  = (const float*)d_in[4];
    const float* Wout = (const float*)d_in[5];
    const float* bout = (const float*)d_in[6];
    float* out = (float*)d_out;

    char* p = (char*)d_ws;
    unsigned short* Wp   = (unsigned short*)p; p += (size_t)32 * 8 * NKK * 64 * 8 * 2;       // 10.5 MB
    unsigned short* WoBf = (unsigned short*)p; p += (size_t)VOUT * HID * 2;                  // 256 KB
    float*          bc   = (float*)p;          p += (size_t)4096 * 4;                        // 16 KB
    int*            bar  = (int*)p;            p += (size_t)4096 * 4;                        // 16 KB
    unsigned short* Xb   = (unsigned short*)p; p += (size_t)T_STEPS * BATCH * DIM * 2;       // 67 MB
    unsigned short* Hblk = (unsigned short*)p; p += (size_t)(T_STEPS + 1) * HSLOT * 2;       // 268 MB

    pack_w    <<<20480, 256, 0, stream>>>(Wih, Whh, Wp);
    pack_bias <<<16,    256, 0, stream>>>(bih, bhh, bc);
    pack_wout <<<512,   256, 0, stream>>>(Wout, WoBf);
    pack_x    <<<130944,256, 0, stream>>>(seq, Xb);
    init_state<<<512,   256, 0, stream>>>(Hblk, bar);

    lstm_persist<<<WGS, 512, 0, stream>>>(Xb, Hblk, Wp, bc, bar);

    head_ls<<<dim3(8, T_STEPS), 256, 0, stream>>>(Hblk, WoBf, bout, out);
}